// Round 15
// baseline (268.367 us; speedup 1.0000x reference)
//
#include <hip/hip_runtime.h>
#include <math.h>

#define NN 50000
#define EE 800000
#define DIN 128
#define HH 256
#define CC 47
#define LK2 264     // LDS row stride in bf16 (256 + 8 pad)
#define GS_BLOCKS 2048

typedef short bf16x8 __attribute__((ext_vector_type(8)));
typedef float f32x4 __attribute__((ext_vector_type(4)));
typedef float f32x2 __attribute__((ext_vector_type(2)));

static __device__ __forceinline__ unsigned short f2bf(float f) {
    unsigned u = __float_as_uint(f);
    u = u + 0x7fff + ((u >> 16) & 1);
    return (unsigned short)(u >> 16);
}
static __device__ __forceinline__ float bflo(unsigned u) { return __uint_as_float(u << 16); }
static __device__ __forceinline__ float bfhi(unsigned u) { return __uint_as_float(u & 0xffff0000u); }

// -- fused prep: bucket-CSR fill (u16) + x->fp8/bf16 + weight repack + mask list
__global__ __launch_bounds__(256) void prep_kernel(
    const float* __restrict__ x, const int* __restrict__ row,
    const int* __restrict__ col, const int* __restrict__ msk,
    const float* __restrict__ w1n, const float* __restrict__ w1s,
    const float* __restrict__ b1n, const float* __restrict__ b1s,
    const float* __restrict__ w2n, const float* __restrict__ w2s,
    int* __restrict__ cnt, unsigned short* __restrict__ bucket,
    unsigned* __restrict__ xq, unsigned* __restrict__ ab,
    unsigned short* __restrict__ WB1, unsigned short* __restrict__ WB2,
    float* __restrict__ bias1, int* __restrict__ mcount, int* __restrict__ mlist)
{
    int t = blockIdx.x * 256 + threadIdx.x;
    if (t < EE) {
        int r = row[t];
        int pos = atomicAdd(&cnt[r], 1);
        if (pos < 64) bucket[r * 64 + pos] = (unsigned short)col[t];
    }
    if (t < NN && msk[t]) {
        int p = atomicAdd(mcount, 1);
        mlist[p] = t;
    }
    if (t < NN * 32) {
        int i = t >> 5, c = t & 31;
        float4 v = *(const float4*)&x[(size_t)i * DIN + c * 4];
        int p = __builtin_amdgcn_cvt_pk_fp8_f32(v.x, v.y, 0, false);
        p = __builtin_amdgcn_cvt_pk_fp8_f32(v.z, v.w, p, true);
        xq[(size_t)i * 32 + c] = (unsigned)p;
        ab[(size_t)i * 128 + 64 + 2 * c]     = (unsigned)f2bf(v.x) | ((unsigned)f2bf(v.y) << 16);
        ab[(size_t)i * 128 + 64 + 2 * c + 1] = (unsigned)f2bf(v.z) | ((unsigned)f2bf(v.w) << 16);
    }
    if (t < 65536) {
        // coalesced reads: consecutive t -> consecutive n within one row k
        int k = t >> 8, n = t & 255;
        float v = (k < 128) ? w1n[k * HH + n] : w1s[(k - 128) * HH + n];
        WB1[n * 256 + k] = f2bf(v);
    } else if (t < 65536 + 24576) {
        int q = t - 65536;
        int k = q / 96, n = q % 96;      // consecutive q -> consecutive n
        float v;
        if (n < 48) v = (n < CC) ? w2n[k * CC + n] : 0.f;
        else { int m = n - 48; v = (m < CC) ? w2s[k * CC + m] : 0.f; }
        WB2[n * 256 + k] = f2bf(v);
    } else if (t < 65536 + 24576 + 256) {
        int n = t - 65536 - 24576;
        bias1[n] = b1n[n] + b1s[n];
    }
}

// ----------------------------------------------- layer-1 gather (fp8 x)
// grid-stride: wave per node; half-wave per edge; single 64-slot batch.
__global__ __launch_bounds__(256) void agg1(const unsigned* __restrict__ xq,
                                            const int* __restrict__ cnt,
                                            const unsigned short* __restrict__ bucket,
                                            unsigned* __restrict__ ab,
                                            float* __restrict__ inv) {
    int wave = threadIdx.x >> 6, lane = threadIdx.x & 63;
    const int h = lane >> 5, hl = lane & 31;
    const int W = gridDim.x * 4;
    for (int i = blockIdx.x * 4 + wave; i < NN; i += W) {
        int e = cnt[i];
        float dvs = fmaxf((float)e, 1.0f);
        if (e > 64) e = 64;
        float A0=0,A1=0,A2=0,A3=0, B0=0,B1=0,B2=0,B3=0;
        float C0=0,C1=0,C2=0,C3=0, D0=0,D1=0,D2=0,D3=0;
        if (e > 0) {
            int myidx = bucket[i * 64 + min(lane, e - 1)];
            int j = 0;
            for (; j + 16 <= e; j += 16) {
                int n0 = __shfl(myidx, j + h);
                int n1 = __shfl(myidx, j + 2 + h);
                int n2 = __shfl(myidx, j + 4 + h);
                int n3 = __shfl(myidx, j + 6 + h);
                int n4 = __shfl(myidx, j + 8 + h);
                int n5 = __shfl(myidx, j + 10 + h);
                int n6 = __shfl(myidx, j + 12 + h);
                int n7 = __shfl(myidx, j + 14 + h);
                unsigned u0 = xq[(size_t)n0 * 32 + hl];
                unsigned u1 = xq[(size_t)n1 * 32 + hl];
                unsigned u2 = xq[(size_t)n2 * 32 + hl];
                unsigned u3 = xq[(size_t)n3 * 32 + hl];
                unsigned u4 = xq[(size_t)n4 * 32 + hl];
                unsigned u5 = xq[(size_t)n5 * 32 + hl];
                unsigned u6 = xq[(size_t)n6 * 32 + hl];
                unsigned u7 = xq[(size_t)n7 * 32 + hl];
                f32x2 l0 = __builtin_amdgcn_cvt_pk_f32_fp8(u0, false);
                f32x2 h0 = __builtin_amdgcn_cvt_pk_f32_fp8(u0, true);
                f32x2 l1 = __builtin_amdgcn_cvt_pk_f32_fp8(u1, false);
                f32x2 h1 = __builtin_amdgcn_cvt_pk_f32_fp8(u1, true);
                f32x2 l2 = __builtin_amdgcn_cvt_pk_f32_fp8(u2, false);
                f32x2 h2 = __builtin_amdgcn_cvt_pk_f32_fp8(u2, true);
                f32x2 l3 = __builtin_amdgcn_cvt_pk_f32_fp8(u3, false);
                f32x2 h3 = __builtin_amdgcn_cvt_pk_f32_fp8(u3, true);
                A0 += l0.x; A1 += l0.y; A2 += h0.x; A3 += h0.y;
                B0 += l1.x; B1 += l1.y; B2 += h1.x; B3 += h1.y;
                C0 += l2.x; C1 += l2.y; C2 += h2.x; C3 += h2.y;
                D0 += l3.x; D1 += l3.y; D2 += h3.x; D3 += h3.y;
                f32x2 l4 = __builtin_amdgcn_cvt_pk_f32_fp8(u4, false);
                f32x2 h4 = __builtin_amdgcn_cvt_pk_f32_fp8(u4, true);
                f32x2 l5 = __builtin_amdgcn_cvt_pk_f32_fp8(u5, false);
                f32x2 h5 = __builtin_amdgcn_cvt_pk_f32_fp8(u5, true);
                f32x2 l6 = __builtin_amdgcn_cvt_pk_f32_fp8(u6, false);
                f32x2 h6 = __builtin_amdgcn_cvt_pk_f32_fp8(u6, true);
                f32x2 l7 = __builtin_amdgcn_cvt_pk_f32_fp8(u7, false);
                f32x2 h7 = __builtin_amdgcn_cvt_pk_f32_fp8(u7, true);
                A0 += l4.x; A1 += l4.y; A2 += h4.x; A3 += h4.y;
                B0 += l5.x; B1 += l5.y; B2 += h5.x; B3 += h5.y;
                C0 += l6.x; C1 += l6.y; C2 += h6.x; C3 += h6.y;
                D0 += l7.x; D1 += l7.y; D2 += h7.x; D3 += h7.y;
            }
            for (; j + 8 <= e; j += 8) {
                int n0 = __shfl(myidx, j + h);
                int n1 = __shfl(myidx, j + 2 + h);
                int n2 = __shfl(myidx, j + 4 + h);
                int n3 = __shfl(myidx, j + 6 + h);
                unsigned u0 = xq[(size_t)n0 * 32 + hl];
                unsigned u1 = xq[(size_t)n1 * 32 + hl];
                unsigned u2 = xq[(size_t)n2 * 32 + hl];
                unsigned u3 = xq[(size_t)n3 * 32 + hl];
                f32x2 l0 = __builtin_amdgcn_cvt_pk_f32_fp8(u0, false);
                f32x2 h0 = __builtin_amdgcn_cvt_pk_f32_fp8(u0, true);
                f32x2 l1 = __builtin_amdgcn_cvt_pk_f32_fp8(u1, false);
                f32x2 h1 = __builtin_amdgcn_cvt_pk_f32_fp8(u1, true);
                f32x2 l2 = __builtin_amdgcn_cvt_pk_f32_fp8(u2, false);
                f32x2 h2 = __builtin_amdgcn_cvt_pk_f32_fp8(u2, true);
                f32x2 l3 = __builtin_amdgcn_cvt_pk_f32_fp8(u3, false);
                f32x2 h3 = __builtin_amdgcn_cvt_pk_f32_fp8(u3, true);
                A0 += l0.x; A1 += l0.y; A2 += h0.x; A3 += h0.y;
                B0 += l1.x; B1 += l1.y; B2 += h1.x; B3 += h1.y;
                C0 += l2.x; C1 += l2.y; C2 += h2.x; C3 += h2.y;
                D0 += l3.x; D1 += l3.y; D2 += h3.x; D3 += h3.y;
            }
            for (; j < e; j += 2) {
                int src = j + h;
                int n = __shfl(myidx, min(src, e - 1));
                unsigned u = xq[(size_t)n * 32 + hl];
                if (src >= e) u = 0u;
                f32x2 lo = __builtin_amdgcn_cvt_pk_f32_fp8(u, false);
                f32x2 hi = __builtin_amdgcn_cvt_pk_f32_fp8(u, true);
                A0 += lo.x; A1 += lo.y; A2 += hi.x; A3 += hi.y;
            }
        }
        float s0 = (A0 + B0) + (C0 + D0);
        float s1 = (A1 + B1) + (C1 + D1);
        float s2 = (A2 + B2) + (C2 + D2);
        float s3 = (A3 + B3) + (C3 + D3);
        s0 += __shfl_xor(s0, 32); s1 += __shfl_xor(s1, 32);
        s2 += __shfl_xor(s2, 32); s3 += __shfl_xor(s3, 32);
        if (h == 0) {
            float sc = 1.0f / dvs;
            if (hl == 0) inv[i] = sc;
            unsigned d0 = (unsigned)f2bf(s0 * sc) | ((unsigned)f2bf(s1 * sc) << 16);
            unsigned d1 = (unsigned)f2bf(s2 * sc) | ((unsigned)f2bf(s3 * sc) << 16);
            *(uint2*)&ab[(size_t)i * 128 + 2 * hl] = make_uint2(d0, d1);
        }
    }
}

// ------------------- FUSED layer-1 + layer-2 GEMM, 64-row / 512-thread blocks
__global__ __launch_bounds__(512) void gemm12_fused(
    const unsigned short* __restrict__ AB,
    const unsigned short* __restrict__ WB1, const unsigned short* __restrict__ WB2,
    const float* __restrict__ bias1,
    const float* __restrict__ b2n, const float* __restrict__ b2s,
    unsigned* __restrict__ znb, float* __restrict__ zsb)
{
    __shared__ unsigned short sA[64 * LK2];
    __shared__ unsigned short sB[32 * LK2];
    __shared__ unsigned short sH[64 * LK2];
    const int tid = threadIdx.x;
    const int i0 = blockIdx.x * 64;
    const int wv = tid >> 6, lane = tid & 63;
    const int g = lane >> 4, l16 = lane & 15;
    const int m0 = (wv & 3) * 16, q0 = (wv >> 2) * 16;

    // stage A-tile 64x256 (2048 int4 chunks, 512 threads x 4)
#pragma unroll
    for (int l = 0; l < 4; ++l) {
        int c = tid + l * 512;
        int r = c >> 5, c8 = (c & 31) * 8;
        int gi = i0 + r;
        int4 v = make_int4(0, 0, 0, 0);
        if (gi < NN) v = *(const int4*)&AB[(size_t)gi * 256 + c8];
        *(int4*)&sA[r * LK2 + c8] = v;
    }

    // pass A: 8 col-blocks of 32 h1-columns
    for (int n0 = 0; n0 < 8; ++n0) {
#pragma unroll
        for (int l = 0; l < 2; ++l) {
            int c = tid + l * 512;             // 0..1023
            int r = c >> 5, c8 = (c & 31) * 8;
            *(int4*)&sB[r * LK2 + c8] = *(const int4*)&WB1[(size_t)(n0 * 32 + r) * 256 + c8];
        }
        __syncthreads();
        f32x4 p0 = {}, p1 = {}, p2 = {}, p3 = {};
        {
            const unsigned short* ar = &sA[(m0 + l16) * LK2 + g * 8];
            const unsigned short* br = &sB[(q0 + l16) * LK2 + g * 8];
            p0 = __builtin_amdgcn_mfma_f32_16x16x32_bf16(*(const bf16x8*)(ar +   0), *(const bf16x8*)(br +   0), p0, 0, 0, 0);
            p1 = __builtin_amdgcn_mfma_f32_16x16x32_bf16(*(const bf16x8*)(ar +  32), *(const bf16x8*)(br +  32), p1, 0, 0, 0);
            p2 = __builtin_amdgcn_mfma_f32_16x16x32_bf16(*(const bf16x8*)(ar +  64), *(const bf16x8*)(br +  64), p2, 0, 0, 0);
            p3 = __builtin_amdgcn_mfma_f32_16x16x32_bf16(*(const bf16x8*)(ar +  96), *(const bf16x8*)(br +  96), p3, 0, 0, 0);
            p0 = __builtin_amdgcn_mfma_f32_16x16x32_bf16(*(const bf16x8*)(ar + 128), *(const bf16x8*)(br + 128), p0, 0, 0, 0);
            p1 = __builtin_amdgcn_mfma_f32_16x16x32_bf16(*(const bf16x8*)(ar + 160), *(const bf16x8*)(br + 160), p1, 0, 0, 0);
            p2 = __builtin_amdgcn_mfma_f32_16x16x32_bf16(*(const bf16x8*)(ar + 192), *(const bf16x8*)(br + 192), p2, 0, 0, 0);
            p3 = __builtin_amdgcn_mfma_f32_16x16x32_bf16(*(const bf16x8*)(ar + 224), *(const bf16x8*)(br + 224), p3, 0, 0, 0);
        }
        f32x4 acc = (p0 + p1) + (p2 + p3);
        int colh = n0 * 32 + q0 + l16;
        float bi = bias1[colh];
#pragma unroll
        for (int r = 0; r < 4; ++r)
            sH[(m0 + g * 4 + r) * LK2 + colh] = f2bf(fmaxf(acc[r] + bi, 0.f));
        __syncthreads();
    }

    // pass B: 3 chunks of 32 output cols from WB2 (96x256)
    for (int m = 0; m < 3; ++m) {
#pragma unroll
        for (int l = 0; l < 2; ++l) {
            int c = tid + l * 512;
            int r = c >> 5, c8 = (c & 31) * 8;
            *(int4*)&sB[r * LK2 + c8] = *(const int4*)&WB2[(size_t)(m * 32 + r) * 256 + c8];
        }
        __syncthreads();
        f32x4 p0 = {}, p1 = {}, p2 = {}, p3 = {};
        {
            const unsigned short* ar = &sH[(m0 + l16) * LK2 + g * 8];
            const unsigned short* br = &sB[(q0 + l16) * LK2 + g * 8];
            p0 = __builtin_amdgcn_mfma_f32_16x16x32_bf16(*(const bf16x8*)(ar +   0), *(const bf16x8*)(br +   0), p0, 0, 0, 0);
            p1 = __builtin_amdgcn_mfma_f32_16x16x32_bf16(*(const bf16x8*)(ar +  32), *(const bf16x8*)(br +  32), p1, 0, 0, 0);
            p2 = __builtin_amdgcn_mfma_f32_16x16x32_bf16(*(const bf16x8*)(ar +  64), *(const bf16x8*)(br +  64), p2, 0, 0, 0);
            p3 = __builtin_amdgcn_mfma_f32_16x16x32_bf16(*(const bf16x8*)(ar +  96), *(const bf16x8*)(br +  96), p3, 0, 0, 0);
            p0 = __builtin_amdgcn_mfma_f32_16x16x32_bf16(*(const bf16x8*)(ar + 128), *(const bf16x8*)(br + 128), p0, 0, 0, 0);
            p1 = __builtin_amdgcn_mfma_f32_16x16x32_bf16(*(const bf16x8*)(ar + 160), *(const bf16x8*)(br + 160), p1, 0, 0, 0);
            p2 = __builtin_amdgcn_mfma_f32_16x16x32_bf16(*(const bf16x8*)(ar + 192), *(const bf16x8*)(br + 192), p2, 0, 0, 0);
            p3 = __builtin_amdgcn_mfma_f32_16x16x32_bf16(*(const bf16x8*)(ar + 224), *(const bf16x8*)(br + 224), p3, 0, 0, 0);
        }
        f32x4 acc = (p0 + p1) + (p2 + p3);
        int c = m * 32 + q0 + l16;
        if (c < 48) {
#pragma unroll
            for (int r = 0; r < 4; ++r) {
                int gi = i0 + m0 + g * 4 + r;
                float v = acc[r];
                float vp = __shfl_down(v, 1);
                if (((l16 & 1) == 0) && gi < NN)
                    znb[(size_t)gi * 24 + (c >> 1)] =
                        (unsigned)f2bf(v) | ((unsigned)f2bf(vp) << 16);
            }
        } else {
            int cz = c - 48;
            float bias = (cz < CC) ? (b2n[cz] + b2s[cz]) : 0.f;
#pragma unroll
            for (int r = 0; r < 4; ++r) {
                int gi = i0 + m0 + g * 4 + r;
                if (gi < NN) zsb[(size_t)gi * 48 + cz] = acc[r] + bias;
            }
        }
        __syncthreads();
    }
}

// --------------- masked loss: HALF-WAVE per node (no fence, no finalize)
__global__ __launch_bounds__(256) void loss_kernel(
    const unsigned* __restrict__ znb, const float* __restrict__ zsb,
    const int* __restrict__ cnt, const unsigned short* __restrict__ bucket,
    const float* __restrict__ inv, const int* __restrict__ y,
    const int* __restrict__ mcount, const int* __restrict__ mlist,
    float* __restrict__ accum)
{
    __shared__ float red[16];
    const int tid = threadIdx.x;
    const int wave = tid >> 6, lane = tid & 63;
    const int half = lane >> 5, hl = lane & 31;
    const int h32 = lane & 32;
    const bool act = hl < 24;
    const int dw = act ? hl : 0;
    const int W = gridDim.x * 8;
    const int M = mcount[0];
    float num = 0.f, den = 0.f;

    for (int p = (blockIdx.x * 4 + wave) * 2 + half; p < M; p += W) {
        int i = mlist[p];
        int e = cnt[i];
        if (e > 64) e = 64;
        float plo[8] = {}, phi[8] = {};
        for (int base = 0; base < e; base += 32) {
            int c2 = min(32, e - base);
            int myidx = bucket[i * 64 + min(base + hl, e - 1)];
            int j = 0;
            for (; j + 8 <= c2; j += 8) {
                unsigned uu[8];
#pragma unroll
                for (int k = 0; k < 8; ++k) {
                    int n = __shfl(myidx, h32 + j + k);
                    uu[k] = znb[(size_t)n * 24 + dw];
                }
#pragma unroll
                for (int k = 0; k < 8; ++k) {
                    plo[k] += bflo(uu[k]); phi[k] += bfhi(uu[k]);
                }
            }
            for (; j + 4 <= c2; j += 4) {
                unsigned uu[4];
#pragma unroll
                for (int k = 0; k < 4; ++k) {
                    int n = __shfl(myidx, h32 + j + k);
                    uu[k] = znb[(size_t)n * 24 + dw];
                }
#pragma unroll
                for (int k = 0; k < 4; ++k) {
                    plo[k] += bflo(uu[k]); phi[k] += bfhi(uu[k]);
                }
            }
            for (; j < c2; ++j) {
                int n = __shfl(myidx, h32 + j);
                unsigned u = znb[(size_t)n * 24 + dw];
                plo[0] += bflo(u); phi[0] += bfhi(u);
            }
        }
        float alo = ((plo[0] + plo[1]) + (plo[2] + plo[3])) +
                    ((plo[4] + plo[5]) + (plo[6] + plo[7]));
        float ahi = ((phi[0] + phi[1]) + (phi[2] + phi[3])) +
                    ((phi[4] + phi[5]) + (phi[6] + phi[7]));

        float sc = inv[i];
        float llo = -1e30f, lhi = -1e30f;
        if (act) {
            float2 zs = *(const float2*)&zsb[(size_t)i * 48 + 2 * hl];
            llo = alo * sc + zs.x;
            lhi = ahi * sc + zs.y;
        }
        if (hl == 23) lhi = -1e30f;      // class 47 invalid
        float mx = fmaxf(llo, lhi);
#pragma unroll
        for (int off = 16; off >= 1; off >>= 1)
            mx = fmaxf(mx, __shfl_xor(mx, off));
        float sm = act ? (__expf(llo - mx) + __expf(lhi - mx)) : 0.f;
#pragma unroll
        for (int off = 16; off >= 1; off >>= 1)
            sm += __shfl_xor(sm, off);
        float lse = mx + __logf(sm);
        int yi = y[i];
        float gl = __shfl(llo, h32 + (yi >> 1));
        float gh = __shfl(lhi, h32 + (yi >> 1));
        float ly = (yi & 1) ? gh : gl;
        if (hl == 0) { num += lse - ly; den += 1.f; }
    }
    if (hl == 0) {
        red[wave * 4 + half * 2]     = num;
        red[wave * 4 + half * 2 + 1] = den;
    }
    __syncthreads();
    if (tid == 0) {
        float n = 0.f, d = 0.f;
#pragma unroll
        for (int k = 0; k < 16; k += 2) { n += red[k]; d += red[k + 1]; }
        atomicAdd(&accum[0], n);
        atomicAdd(&accum[1], d);
    }
}

__global__ void finalize_kernel(const float* __restrict__ accum, float* __restrict__ out) {
    out[0] = accum[0] / fmaxf(accum[1], 1.0f);
}

// ---------------------------------------------------------------- launch
extern "C" void kernel_launch(void* const* d_in, const int* in_sizes, int n_in,
                              void* d_out, int out_size, void* d_ws, size_t ws_size,
                              hipStream_t stream) {
    const float* x   = (const float*)d_in[0];
    const int*   row = (const int*)d_in[1];
    const int*   col = (const int*)d_in[2];
    const int*   y   = (const int*)d_in[3];
    const int*   msk = (const int*)d_in[4];
    const float* w1n = (const float*)d_in[5];
    const float* b1n = (const float*)d_in[6];
    const float* w1s = (const float*)d_in[7];
    const float* b1s = (const float*)d_in[8];
    const float* w2n = (const float*)d_in[9];
    const float* b2n = (const float*)d_in[10];
    const float* w2s = (const float*)d_in[11];
    const float* b2s = (const float*)d_in[12];
    float* out = (float*)d_out;

    float* ws      = (float*)d_ws;
    float* accum   = ws;                                  // [0]num [1]den
    int*   mcount  = (int*)(ws + 32);
    int*   cnt     = (int*)(ws + 64);                     // 50048 ints
    unsigned short* bucket = (unsigned short*)(cnt + 50048);  // 3.2M ushorts
    unsigned* xq   = (unsigned*)(bucket + 3200000);       // NN*32 (fp8 x)
    unsigned* ab   = xq + (size_t)NN * 32;                // NN*128 dwords
    unsigned* znb  = ab + (size_t)NN * 128;               // NN*24
    float* zsb     = (float*)(znb + (size_t)NN * 24);     // NN*48
    unsigned short* WB1 = (unsigned short*)(zsb + (size_t)NN * 48);  // 256*256
    unsigned short* WB2 = WB1 + 65536;                    // 96*256
    float* bias1   = (float*)(WB2 + 24576);               // 256
    int*   mlist   = (int*)(bias1 + 256);                 // 50048
    float* inv     = (float*)(mlist + 50048);             // 50048

    (void)hipMemsetAsync(accum, 0, (64 + 50048) * sizeof(float), stream); // accum+mcount+cnt

    prep_kernel<<<(NN * 32 + 255) / 256, 256, 0, stream>>>(
        x, row, col, msk, w1n, w1s, b1n, b1s, w2n, w2s,
        cnt, bucket, xq, ab, WB1, WB2, bias1, mcount, mlist);

    agg1<<<GS_BLOCKS, 256, 0, stream>>>(xq, cnt, bucket, ab, inv);

    gemm12_fused<<<(NN + 63) / 64, 512, 0, stream>>>(
        (const unsigned short*)ab, WB1, WB2, bias1, b2n, b2s, znb, zsb);

    loss_kernel<<<GS_BLOCKS, 256, 0, stream>>>(
        znb, zsb, cnt, bucket, inv, y, mcount, mlist, accum);

    finalize_kernel<<<1, 1, 0, stream>>>(accum, out);
}

// Round 16
// 255.396 us; speedup vs baseline: 1.0508x; 1.0508x over previous
//
#include <hip/hip_runtime.h>
#include <math.h>

#define NN 50000
#define EE 800000
#define DIN 128
#define HH 256
#define CC 47
#define LK2 264     // LDS row stride in bf16 (256 + 8 pad)
#define GS_BLOCKS 2048

typedef short bf16x8 __attribute__((ext_vector_type(8)));
typedef float f32x4 __attribute__((ext_vector_type(4)));
typedef float f32x2 __attribute__((ext_vector_type(2)));

static __device__ __forceinline__ unsigned short f2bf(float f) {
    unsigned u = __float_as_uint(f);
    u = u + 0x7fff + ((u >> 16) & 1);
    return (unsigned short)(u >> 16);
}
static __device__ __forceinline__ float bflo(unsigned u) { return __uint_as_float(u << 16); }
static __device__ __forceinline__ float bfhi(unsigned u) { return __uint_as_float(u & 0xffff0000u); }

// -- fused prep: bucket-CSR fill (u16) + x->fp8/bf16 + weight repack + mask list
__global__ __launch_bounds__(256) void prep_kernel(
    const float* __restrict__ x, const int* __restrict__ row,
    const int* __restrict__ col, const int* __restrict__ msk,
    const float* __restrict__ w1n, const float* __restrict__ w1s,
    const float* __restrict__ b1n, const float* __restrict__ b1s,
    const float* __restrict__ w2n, const float* __restrict__ w2s,
    int* __restrict__ cnt, unsigned short* __restrict__ bucket,
    unsigned* __restrict__ xq, unsigned* __restrict__ ab,
    unsigned short* __restrict__ WB1, unsigned short* __restrict__ WB2,
    float* __restrict__ bias1, int* __restrict__ mcount, int* __restrict__ mlist)
{
    int t = blockIdx.x * 256 + threadIdx.x;
    if (t < EE) {
        int r = row[t];
        int pos = atomicAdd(&cnt[r], 1);
        if (pos < 64) bucket[r * 64 + pos] = (unsigned short)col[t];
    }
    if (t < NN && msk[t]) {
        int p = atomicAdd(mcount, 1);
        mlist[p] = t;
    }
    if (t < NN * 32) {
        int i = t >> 5, c = t & 31;
        float4 v = *(const float4*)&x[(size_t)i * DIN + c * 4];
        int p = __builtin_amdgcn_cvt_pk_fp8_f32(v.x, v.y, 0, false);
        p = __builtin_amdgcn_cvt_pk_fp8_f32(v.z, v.w, p, true);
        xq[(size_t)i * 32 + c] = (unsigned)p;
        ab[(size_t)i * 128 + 64 + 2 * c]     = (unsigned)f2bf(v.x) | ((unsigned)f2bf(v.y) << 16);
        ab[(size_t)i * 128 + 64 + 2 * c + 1] = (unsigned)f2bf(v.z) | ((unsigned)f2bf(v.w) << 16);
    }
    if (t < 65536) {
        // coalesced reads: consecutive t -> consecutive n within one row k
        int k = t >> 8, n = t & 255;
        float v = (k < 128) ? w1n[k * HH + n] : w1s[(k - 128) * HH + n];
        WB1[n * 256 + k] = f2bf(v);
    } else if (t < 65536 + 24576) {
        int q = t - 65536;
        int k = q / 96, n = q % 96;      // consecutive q -> consecutive n
        float v;
        if (n < 48) v = (n < CC) ? w2n[k * CC + n] : 0.f;
        else { int m = n - 48; v = (m < CC) ? w2s[k * CC + m] : 0.f; }
        WB2[n * 256 + k] = f2bf(v);
    } else if (t < 65536 + 24576 + 256) {
        int n = t - 65536 - 24576;
        bias1[n] = b1n[n] + b1s[n];
    }
}

// ----------------------------------------------- layer-1 gather (fp8 x)
// grid-stride: wave per node; half-wave per edge; single 64-slot batch.
__global__ __launch_bounds__(256) void agg1(const unsigned* __restrict__ xq,
                                            const int* __restrict__ cnt,
                                            const unsigned short* __restrict__ bucket,
                                            unsigned* __restrict__ ab,
                                            float* __restrict__ inv) {
    int wave = threadIdx.x >> 6, lane = threadIdx.x & 63;
    const int h = lane >> 5, hl = lane & 31;
    const int W = gridDim.x * 4;
    for (int i = blockIdx.x * 4 + wave; i < NN; i += W) {
        int e = cnt[i];
        float dvs = fmaxf((float)e, 1.0f);
        if (e > 64) e = 64;
        float A0=0,A1=0,A2=0,A3=0, B0=0,B1=0,B2=0,B3=0;
        float C0=0,C1=0,C2=0,C3=0, D0=0,D1=0,D2=0,D3=0;
        if (e > 0) {
            int myidx = bucket[i * 64 + min(lane, e - 1)];
            int j = 0;
            for (; j + 16 <= e; j += 16) {
                int n0 = __shfl(myidx, j + h);
                int n1 = __shfl(myidx, j + 2 + h);
                int n2 = __shfl(myidx, j + 4 + h);
                int n3 = __shfl(myidx, j + 6 + h);
                int n4 = __shfl(myidx, j + 8 + h);
                int n5 = __shfl(myidx, j + 10 + h);
                int n6 = __shfl(myidx, j + 12 + h);
                int n7 = __shfl(myidx, j + 14 + h);
                unsigned u0 = xq[(size_t)n0 * 32 + hl];
                unsigned u1 = xq[(size_t)n1 * 32 + hl];
                unsigned u2 = xq[(size_t)n2 * 32 + hl];
                unsigned u3 = xq[(size_t)n3 * 32 + hl];
                unsigned u4 = xq[(size_t)n4 * 32 + hl];
                unsigned u5 = xq[(size_t)n5 * 32 + hl];
                unsigned u6 = xq[(size_t)n6 * 32 + hl];
                unsigned u7 = xq[(size_t)n7 * 32 + hl];
                f32x2 l0 = __builtin_amdgcn_cvt_pk_f32_fp8(u0, false);
                f32x2 h0 = __builtin_amdgcn_cvt_pk_f32_fp8(u0, true);
                f32x2 l1 = __builtin_amdgcn_cvt_pk_f32_fp8(u1, false);
                f32x2 h1 = __builtin_amdgcn_cvt_pk_f32_fp8(u1, true);
                f32x2 l2 = __builtin_amdgcn_cvt_pk_f32_fp8(u2, false);
                f32x2 h2 = __builtin_amdgcn_cvt_pk_f32_fp8(u2, true);
                f32x2 l3 = __builtin_amdgcn_cvt_pk_f32_fp8(u3, false);
                f32x2 h3 = __builtin_amdgcn_cvt_pk_f32_fp8(u3, true);
                A0 += l0.x; A1 += l0.y; A2 += h0.x; A3 += h0.y;
                B0 += l1.x; B1 += l1.y; B2 += h1.x; B3 += h1.y;
                C0 += l2.x; C1 += l2.y; C2 += h2.x; C3 += h2.y;
                D0 += l3.x; D1 += l3.y; D2 += h3.x; D3 += h3.y;
                f32x2 l4 = __builtin_amdgcn_cvt_pk_f32_fp8(u4, false);
                f32x2 h4 = __builtin_amdgcn_cvt_pk_f32_fp8(u4, true);
                f32x2 l5 = __builtin_amdgcn_cvt_pk_f32_fp8(u5, false);
                f32x2 h5 = __builtin_amdgcn_cvt_pk_f32_fp8(u5, true);
                f32x2 l6 = __builtin_amdgcn_cvt_pk_f32_fp8(u6, false);
                f32x2 h6 = __builtin_amdgcn_cvt_pk_f32_fp8(u6, true);
                f32x2 l7 = __builtin_amdgcn_cvt_pk_f32_fp8(u7, false);
                f32x2 h7 = __builtin_amdgcn_cvt_pk_f32_fp8(u7, true);
                A0 += l4.x; A1 += l4.y; A2 += h4.x; A3 += h4.y;
                B0 += l5.x; B1 += l5.y; B2 += h5.x; B3 += h5.y;
                C0 += l6.x; C1 += l6.y; C2 += h6.x; C3 += h6.y;
                D0 += l7.x; D1 += l7.y; D2 += h7.x; D3 += h7.y;
            }
            for (; j + 8 <= e; j += 8) {
                int n0 = __shfl(myidx, j + h);
                int n1 = __shfl(myidx, j + 2 + h);
                int n2 = __shfl(myidx, j + 4 + h);
                int n3 = __shfl(myidx, j + 6 + h);
                unsigned u0 = xq[(size_t)n0 * 32 + hl];
                unsigned u1 = xq[(size_t)n1 * 32 + hl];
                unsigned u2 = xq[(size_t)n2 * 32 + hl];
                unsigned u3 = xq[(size_t)n3 * 32 + hl];
                f32x2 l0 = __builtin_amdgcn_cvt_pk_f32_fp8(u0, false);
                f32x2 h0 = __builtin_amdgcn_cvt_pk_f32_fp8(u0, true);
                f32x2 l1 = __builtin_amdgcn_cvt_pk_f32_fp8(u1, false);
                f32x2 h1 = __builtin_amdgcn_cvt_pk_f32_fp8(u1, true);
                f32x2 l2 = __builtin_amdgcn_cvt_pk_f32_fp8(u2, false);
                f32x2 h2 = __builtin_amdgcn_cvt_pk_f32_fp8(u2, true);
                f32x2 l3 = __builtin_amdgcn_cvt_pk_f32_fp8(u3, false);
                f32x2 h3 = __builtin_amdgcn_cvt_pk_f32_fp8(u3, true);
                A0 += l0.x; A1 += l0.y; A2 += h0.x; A3 += h0.y;
                B0 += l1.x; B1 += l1.y; B2 += h1.x; B3 += h1.y;
                C0 += l2.x; C1 += l2.y; C2 += h2.x; C3 += h2.y;
                D0 += l3.x; D1 += l3.y; D2 += h3.x; D3 += h3.y;
            }
            for (; j < e; j += 2) {
                int src = j + h;
                int n = __shfl(myidx, min(src, e - 1));
                unsigned u = xq[(size_t)n * 32 + hl];
                if (src >= e) u = 0u;
                f32x2 lo = __builtin_amdgcn_cvt_pk_f32_fp8(u, false);
                f32x2 hi = __builtin_amdgcn_cvt_pk_f32_fp8(u, true);
                A0 += lo.x; A1 += lo.y; A2 += hi.x; A3 += hi.y;
            }
        }
        float s0 = (A0 + B0) + (C0 + D0);
        float s1 = (A1 + B1) + (C1 + D1);
        float s2 = (A2 + B2) + (C2 + D2);
        float s3 = (A3 + B3) + (C3 + D3);
        s0 += __shfl_xor(s0, 32); s1 += __shfl_xor(s1, 32);
        s2 += __shfl_xor(s2, 32); s3 += __shfl_xor(s3, 32);
        if (h == 0) {
            float sc = 1.0f / dvs;
            if (hl == 0) inv[i] = sc;
            unsigned d0 = (unsigned)f2bf(s0 * sc) | ((unsigned)f2bf(s1 * sc) << 16);
            unsigned d1 = (unsigned)f2bf(s2 * sc) | ((unsigned)f2bf(s3 * sc) << 16);
            *(uint2*)&ab[(size_t)i * 128 + 2 * hl] = make_uint2(d0, d1);
        }
    }
}

// ------------------- FUSED layer-1 + layer-2 GEMM (R14 shape: 32-row/256-thr)
__global__ __launch_bounds__(256) void gemm12_fused(
    const unsigned short* __restrict__ AB,
    const unsigned short* __restrict__ WB1, const unsigned short* __restrict__ WB2,
    const float* __restrict__ bias1,
    const float* __restrict__ b2n, const float* __restrict__ b2s,
    unsigned* __restrict__ znb, float* __restrict__ zsb)
{
    __shared__ unsigned short sA[32 * LK2];
    __shared__ unsigned short sB[32 * LK2];
    __shared__ unsigned short sH[32 * LK2];
    const int tid = threadIdx.x;
    const int i0 = blockIdx.x * 32;
    const int wv = tid >> 6, lane = tid & 63;
    const int g = lane >> 4, l16 = lane & 15;
    const int m0 = (wv & 1) * 16, q0 = (wv >> 1) * 16;

#pragma unroll
    for (int l = 0; l < 4; ++l) {
        int c = tid + l * 256;
        int r = c >> 5, c8 = (c & 31) * 8;
        int gi = i0 + r;
        int4 v = make_int4(0, 0, 0, 0);
        if (gi < NN) v = *(const int4*)&AB[(size_t)gi * 256 + c8];
        *(int4*)&sA[r * LK2 + c8] = v;
    }

    for (int n0 = 0; n0 < 8; ++n0) {
#pragma unroll
        for (int l = 0; l < 4; ++l) {
            int c = tid + l * 256;
            int r = c >> 5, c8 = (c & 31) * 8;
            *(int4*)&sB[r * LK2 + c8] = *(const int4*)&WB1[(size_t)(n0 * 32 + r) * 256 + c8];
        }
        __syncthreads();
        f32x4 p0 = {}, p1 = {}, p2 = {}, p3 = {};
        {
            const unsigned short* ar = &sA[(m0 + l16) * LK2 + g * 8];
            const unsigned short* br = &sB[(q0 + l16) * LK2 + g * 8];
            p0 = __builtin_amdgcn_mfma_f32_16x16x32_bf16(*(const bf16x8*)(ar +   0), *(const bf16x8*)(br +   0), p0, 0, 0, 0);
            p1 = __builtin_amdgcn_mfma_f32_16x16x32_bf16(*(const bf16x8*)(ar +  32), *(const bf16x8*)(br +  32), p1, 0, 0, 0);
            p2 = __builtin_amdgcn_mfma_f32_16x16x32_bf16(*(const bf16x8*)(ar +  64), *(const bf16x8*)(br +  64), p2, 0, 0, 0);
            p3 = __builtin_amdgcn_mfma_f32_16x16x32_bf16(*(const bf16x8*)(ar +  96), *(const bf16x8*)(br +  96), p3, 0, 0, 0);
            p0 = __builtin_amdgcn_mfma_f32_16x16x32_bf16(*(const bf16x8*)(ar + 128), *(const bf16x8*)(br + 128), p0, 0, 0, 0);
            p1 = __builtin_amdgcn_mfma_f32_16x16x32_bf16(*(const bf16x8*)(ar + 160), *(const bf16x8*)(br + 160), p1, 0, 0, 0);
            p2 = __builtin_amdgcn_mfma_f32_16x16x32_bf16(*(const bf16x8*)(ar + 192), *(const bf16x8*)(br + 192), p2, 0, 0, 0);
            p3 = __builtin_amdgcn_mfma_f32_16x16x32_bf16(*(const bf16x8*)(ar + 224), *(const bf16x8*)(br + 224), p3, 0, 0, 0);
        }
        f32x4 acc = (p0 + p1) + (p2 + p3);
        int colh = n0 * 32 + q0 + l16;
        float bi = bias1[colh];
#pragma unroll
        for (int r = 0; r < 4; ++r)
            sH[(m0 + g * 4 + r) * LK2 + colh] = f2bf(fmaxf(acc[r] + bi, 0.f));
        __syncthreads();
    }

    for (int m = 0; m < 3; ++m) {
#pragma unroll
        for (int l = 0; l < 4; ++l) {
            int c = tid + l * 256;
            int r = c >> 5, c8 = (c & 31) * 8;
            *(int4*)&sB[r * LK2 + c8] = *(const int4*)&WB2[(size_t)(m * 32 + r) * 256 + c8];
        }
        __syncthreads();
        f32x4 p0 = {}, p1 = {}, p2 = {}, p3 = {};
        {
            const unsigned short* ar = &sH[(m0 + l16) * LK2 + g * 8];
            const unsigned short* br = &sB[(q0 + l16) * LK2 + g * 8];
            p0 = __builtin_amdgcn_mfma_f32_16x16x32_bf16(*(const bf16x8*)(ar +   0), *(const bf16x8*)(br +   0), p0, 0, 0, 0);
            p1 = __builtin_amdgcn_mfma_f32_16x16x32_bf16(*(const bf16x8*)(ar +  32), *(const bf16x8*)(br +  32), p1, 0, 0, 0);
            p2 = __builtin_amdgcn_mfma_f32_16x16x32_bf16(*(const bf16x8*)(ar +  64), *(const bf16x8*)(br +  64), p2, 0, 0, 0);
            p3 = __builtin_amdgcn_mfma_f32_16x16x32_bf16(*(const bf16x8*)(ar +  96), *(const bf16x8*)(br +  96), p3, 0, 0, 0);
            p0 = __builtin_amdgcn_mfma_f32_16x16x32_bf16(*(const bf16x8*)(ar + 128), *(const bf16x8*)(br + 128), p0, 0, 0, 0);
            p1 = __builtin_amdgcn_mfma_f32_16x16x32_bf16(*(const bf16x8*)(ar + 160), *(const bf16x8*)(br + 160), p1, 0, 0, 0);
            p2 = __builtin_amdgcn_mfma_f32_16x16x32_bf16(*(const bf16x8*)(ar + 192), *(const bf16x8*)(br + 192), p2, 0, 0, 0);
            p3 = __builtin_amdgcn_mfma_f32_16x16x32_bf16(*(const bf16x8*)(ar + 224), *(const bf16x8*)(br + 224), p3, 0, 0, 0);
        }
        f32x4 acc = (p0 + p1) + (p2 + p3);
        int c = m * 32 + q0 + l16;
        if (c < 48) {
#pragma unroll
            for (int r = 0; r < 4; ++r) {
                int gi = i0 + m0 + g * 4 + r;
                float v = acc[r];
                float vp = __shfl_down(v, 1);
                if (((l16 & 1) == 0) && gi < NN)
                    znb[(size_t)gi * 24 + (c >> 1)] =
                        (unsigned)f2bf(v) | ((unsigned)f2bf(vp) << 16);
            }
        } else {
            int cz = c - 48;
            float bias = (cz < CC) ? (b2n[cz] + b2s[cz]) : 0.f;
#pragma unroll
            for (int r = 0; r < 4; ++r) {
                int gi = i0 + m0 + g * 4 + r;
                if (gi < NN) zsb[(size_t)gi * 48 + cz] = acc[r] + bias;
            }
        }
        __syncthreads();
    }
}

// --------------- masked loss: HALF-WAVE per node (no fence, no finalize)
__global__ __launch_bounds__(256) void loss_kernel(
    const unsigned* __restrict__ znb, const float* __restrict__ zsb,
    const int* __restrict__ cnt, const unsigned short* __restrict__ bucket,
    const float* __restrict__ inv, const int* __restrict__ y,
    const int* __restrict__ mcount, const int* __restrict__ mlist,
    float* __restrict__ accum)
{
    __shared__ float red[16];
    const int tid = threadIdx.x;
    const int wave = tid >> 6, lane = tid & 63;
    const int half = lane >> 5, hl = lane & 31;
    const int h32 = lane & 32;
    const bool act = hl < 24;
    const int dw = act ? hl : 0;
    const int W = gridDim.x * 8;
    const int M = mcount[0];
    float num = 0.f, den = 0.f;

    for (int p = (blockIdx.x * 4 + wave) * 2 + half; p < M; p += W) {
        int i = mlist[p];
        int e = cnt[i];
        if (e > 64) e = 64;
        float plo[8] = {}, phi[8] = {};
        for (int base = 0; base < e; base += 32) {
            int c2 = min(32, e - base);
            int myidx = bucket[i * 64 + min(base + hl, e - 1)];
            int j = 0;
            for (; j + 8 <= c2; j += 8) {
                unsigned uu[8];
#pragma unroll
                for (int k = 0; k < 8; ++k) {
                    int n = __shfl(myidx, h32 + j + k);
                    uu[k] = znb[(size_t)n * 24 + dw];
                }
#pragma unroll
                for (int k = 0; k < 8; ++k) {
                    plo[k] += bflo(uu[k]); phi[k] += bfhi(uu[k]);
                }
            }
            for (; j + 4 <= c2; j += 4) {
                unsigned uu[4];
#pragma unroll
                for (int k = 0; k < 4; ++k) {
                    int n = __shfl(myidx, h32 + j + k);
                    uu[k] = znb[(size_t)n * 24 + dw];
                }
#pragma unroll
                for (int k = 0; k < 4; ++k) {
                    plo[k] += bflo(uu[k]); phi[k] += bfhi(uu[k]);
                }
            }
            for (; j < c2; ++j) {
                int n = __shfl(myidx, h32 + j);
                unsigned u = znb[(size_t)n * 24 + dw];
                plo[0] += bflo(u); phi[0] += bfhi(u);
            }
        }
        float alo = ((plo[0] + plo[1]) + (plo[2] + plo[3])) +
                    ((plo[4] + plo[5]) + (plo[6] + plo[7]));
        float ahi = ((phi[0] + phi[1]) + (phi[2] + phi[3])) +
                    ((phi[4] + phi[5]) + (phi[6] + phi[7]));

        float sc = inv[i];
        float llo = -1e30f, lhi = -1e30f;
        if (act) {
            float2 zs = *(const float2*)&zsb[(size_t)i * 48 + 2 * hl];
            llo = alo * sc + zs.x;
            lhi = ahi * sc + zs.y;
        }
        if (hl == 23) lhi = -1e30f;      // class 47 invalid
        float mx = fmaxf(llo, lhi);
#pragma unroll
        for (int off = 16; off >= 1; off >>= 1)
            mx = fmaxf(mx, __shfl_xor(mx, off));
        float sm = act ? (__expf(llo - mx) + __expf(lhi - mx)) : 0.f;
#pragma unroll
        for (int off = 16; off >= 1; off >>= 1)
            sm += __shfl_xor(sm, off);
        float lse = mx + __logf(sm);
        int yi = y[i];
        float gl = __shfl(llo, h32 + (yi >> 1));
        float gh = __shfl(lhi, h32 + (yi >> 1));
        float ly = (yi & 1) ? gh : gl;
        if (hl == 0) { num += lse - ly; den += 1.f; }
    }
    if (hl == 0) {
        red[wave * 4 + half * 2]     = num;
        red[wave * 4 + half * 2 + 1] = den;
    }
    __syncthreads();
    if (tid == 0) {
        float n = 0.f, d = 0.f;
#pragma unroll
        for (int k = 0; k < 16; k += 2) { n += red[k]; d += red[k + 1]; }
        atomicAdd(&accum[0], n);
        atomicAdd(&accum[1], d);
    }
}

__global__ void finalize_kernel(const float* __restrict__ accum, float* __restrict__ out) {
    out[0] = accum[0] / fmaxf(accum[1], 1.0f);
}

// ---------------------------------------------------------------- launch
extern "C" void kernel_launch(void* const* d_in, const int* in_sizes, int n_in,
                              void* d_out, int out_size, void* d_ws, size_t ws_size,
                              hipStream_t stream) {
    const float* x   = (const float*)d_in[0];
    const int*   row = (const int*)d_in[1];
    const int*   col = (const int*)d_in[2];
    const int*   y   = (const int*)d_in[3];
    const int*   msk = (const int*)d_in[4];
    const float* w1n = (const float*)d_in[5];
    const float* b1n = (const float*)d_in[6];
    const float* w1s = (const float*)d_in[7];
    const float* b1s = (const float*)d_in[8];
    const float* w2n = (const float*)d_in[9];
    const float* b2n = (const float*)d_in[10];
    const float* w2s = (const float*)d_in[11];
    const float* b2s = (const float*)d_in[12];
    float* out = (float*)d_out;

    float* ws      = (float*)d_ws;
    float* accum   = ws;                                  // [0]num [1]den
    int*   mcount  = (int*)(ws + 32);
    int*   cnt     = (int*)(ws + 64);                     // 50048 ints
    unsigned short* bucket = (unsigned short*)(cnt + 50048);  // 3.2M ushorts
    unsigned* xq   = (unsigned*)(bucket + 3200000);       // NN*32 (fp8 x)
    unsigned* ab   = xq + (size_t)NN * 32;                // NN*128 dwords
    unsigned* znb  = ab + (size_t)NN * 128;               // NN*24
    float* zsb     = (float*)(znb + (size_t)NN * 24);     // NN*48
    unsigned short* WB1 = (unsigned short*)(zsb + (size_t)NN * 48);  // 256*256
    unsigned short* WB2 = WB1 + 65536;                    // 96*256
    float* bias1   = (float*)(WB2 + 24576);               // 256
    int*   mlist   = (int*)(bias1 + 256);                 // 50048
    float* inv     = (float*)(mlist + 50048);             // 50048

    (void)hipMemsetAsync(accum, 0, (64 + 50048) * sizeof(float), stream); // accum+mcount+cnt

    prep_kernel<<<(NN * 32 + 255) / 256, 256, 0, stream>>>(
        x, row, col, msk, w1n, w1s, b1n, b1s, w2n, w2s,
        cnt, bucket, xq, ab, WB1, WB2, bias1, mcount, mlist);

    agg1<<<GS_BLOCKS, 256, 0, stream>>>(xq, cnt, bucket, ab, inv);

    gemm12_fused<<<(NN + 31) / 32, 256, 0, stream>>>(
        (const unsigned short*)ab, WB1, WB2, bias1, b2n, b2s, znb, zsb);

    loss_kernel<<<GS_BLOCKS, 256, 0, stream>>>(
        znb, zsb, cnt, bucket, inv, y, mcount, mlist, accum);

    finalize_kernel<<<1, 1, 0, stream>>>(accum, out);
}